// Round 4
// baseline (485.994 us; speedup 1.0000x reference)
//
#include <hip/hip_runtime.h>
#include <stdint.h>

#define OUT_F 4096
#define IN_F  4096
#define MROWS 8192            // 4*2048
#define NTILE (IN_F / 64)     // 64 K-tiles of 64

typedef __attribute__((ext_vector_type(8))) short  shortx8;   // 8 bf16 = 4 VGPRs
typedef __attribute__((ext_vector_type(4))) float  floatx4;

// fp32 -> bf16 bits, round-to-nearest-even
__device__ __forceinline__ unsigned short f32_to_bf16(float f) {
    unsigned int u = __builtin_bit_cast(unsigned int, f);
    u += 0x7FFFu + ((u >> 16) & 1u);
    return (unsigned short)(u >> 16);
}

// ---------------- preprocessing, fully coalesced grid-stride ----------------
// Old version: lane read 64B contiguous (stride-64B across lanes) -> ~1.5TB/s.
// Now: lane i handles quad i -> 16B/lane lane-contiguous loads (1KB/wave/inst),
// 8B/lane stores.  303MB total -> expect ~55us at HBM roofline.
#define XQUADS (MROWS * IN_F / 4)     // 8,388,608
#define WQUADS (OUT_F * IN_F / 4)     // 4,194,304
#define PRE_XBLK 4096
#define PRE_WBLK 2048
__global__ void __launch_bounds__(256)
preprocess_kernel(const float* __restrict__ x, short* __restrict__ xb,
                  const int* __restrict__ q, const float* __restrict__ s,
                  short* __restrict__ wb) {
    const int b = blockIdx.x;
    if (b < PRE_XBLK) {
        const float4* xi = (const float4*)x;
        ushort4*      xo = (ushort4*)xb;
        for (int i = b * 256 + (int)threadIdx.x; i < XQUADS; i += PRE_XBLK * 256) {
            float4 v = xi[i];
            ushort4 o;
            o.x = f32_to_bf16(v.x); o.y = f32_to_bf16(v.y);
            o.z = f32_to_bf16(v.z); o.w = f32_to_bf16(v.w);
            xo[i] = o;
        }
    } else {
        const int4* qi = (const int4*)q;
        ushort4*    wo = (ushort4*)wb;
        for (int i = (b - PRE_XBLK) * 256 + (int)threadIdx.x; i < WQUADS; i += PRE_WBLK * 256) {
            int4 a = qi[i];
            float sc = s[i >> 4];             // 4 elems per quad; 16 quads per 64-block
            ushort4 o;
            o.x = f32_to_bf16((float)a.x * sc); o.y = f32_to_bf16((float)a.y * sc);
            o.z = f32_to_bf16((float)a.z * sc); o.w = f32_to_bf16((float)a.w * sc);
            wo[i] = o;
        }
    }
}

// ---------------- 256x256 8-phase bf16 GEMM, WAR-grouped MFMA/DS interleave ----------------
// C[M,N] = A[M,K] * B[N,K]^T + bias.  BM=BN=256, BK=64, 8 waves (2M x 4N),
// per-wave output 128x64.  LDS 128 KiB: 2 bufs x (A 256x64 + B 256x64) bf16.
//
// R3 post-mortem: register reuse (af/b0/b1) forces RDs AFTER the whole 16-MFMA
// cluster (WAR), so each phase = MFMA burst (621cyc) THEN LDS burst (384-768cyc)
// serially across lockstepped waves.  Fix (zero extra registers): split into
// groups {4 MFMAs consuming af[mt]} -> {reload af[mt]}, so reads issue 4 MFMAs
// in.  PH1's b1 is dead at phase start (consumed prev P4) -> RD_B1 moves first.
// Per-acc accumulation order unchanged (ks0 then ks1) -> bitwise-identical.
//
// Phase schedule / staging / vmcnt ledger identical to R3 (proofs unchanged):
//   P1: VMC(8);  BAR; ST U3(t+1)->NXT; RD b1(t); 16 MFMA(0,0);            BAR
//   P2: VMC(8);  BAR; ST U0(t+2)->CUR; 4x{4 MFMA(0,2) ; rd af47[mt](t)};  BAR
//   P3: VMC(6);  BAR; ST U1(t+2)->CUR; 2x{8 MFMA(4,0) ; rd b0[nt](t+1)};  BAR
//   P4: VMC(10); BAR; ST U2(t+2)->CUR; 4x{4 MFMA(4,2) ; rd af03[mt](t+1)};BAR

#define BAR()  asm volatile("s_barrier" ::: "memory")
#define VMC(n) asm volatile("s_waitcnt vmcnt(" #n ")" ::: "memory")
#define SGB(mask, n) __builtin_amdgcn_sched_group_barrier((mask), (n), 0)

#define GLD(gp, lo) __builtin_amdgcn_global_load_lds( \
    (const __attribute__((address_space(1))) uint32_t*)(gp), \
    (__attribute__((address_space(3))) uint32_t*)(smem + (lo)), 16, 0, 0)

// d = K-tile offset (units of 64 elems) from current gA/gB; BO = dest buffer byte offset
#define ST_U0(d, BO) do { GLD(gA + (d)*64,            (BO) + lbA        ); \
                          GLD(gA + (d)*64 + 128*IN_F, (BO) + lbA + 16384); } while (0)
#define ST_U3(d, BO) do { GLD(gA + (d)*64 +  64*IN_F, (BO) + lbA +  8192); \
                          GLD(gA + (d)*64 + 192*IN_F, (BO) + lbA + 24576); } while (0)
#define ST_U1(d, BO) do { GLD(gB + (d)*64,            (BO) + lbB        ); \
                          GLD(gB + (d)*64 + 128*IN_F, (BO) + lbB + 16384); } while (0)
#define ST_U2(d, BO) do { GLD(gB + (d)*64 +  32*IN_F, (BO) + lbB +  4096); \
                          GLD(gB + (d)*64 + 160*IN_F, (BO) + lbB + 20480); } while (0)

// ds_read addressing: ks-XOR pre-folded into two base offsets -> base + imm disp.
#define LDA(mt, KS, BO, EX) (*(const shortx8*)(smem + (BO) + ((KS) ? offA1 : offA0) + (EX) + (mt)*2048))
#define LDB(nt, KS, BO)     (*(const shortx8*)(smem + (BO) + ((KS) ? offB1 : offB0) + (nt)*2048))

#define RD_A03(BO) do { _Pragma("unroll") \
    for (int mt_ = 0; mt_ < 4; ++mt_) { af[mt_][0] = LDA(mt_,0,BO,0);    af[mt_][1] = LDA(mt_,1,BO,0);    } } while (0)
#define RD_A47(BO) do { _Pragma("unroll") \
    for (int mt_ = 0; mt_ < 4; ++mt_) { af[mt_][0] = LDA(mt_,0,BO,8192); af[mt_][1] = LDA(mt_,1,BO,8192); } } while (0)
#define RD_B0(BO) do { b0[0][0]=LDB(0,0,BO); b0[0][1]=LDB(0,1,BO); \
                       b0[1][0]=LDB(1,0,BO); b0[1][1]=LDB(1,1,BO); } while (0)
#define RD_B1(BO) do { b1[0][0]=LDB(2,0,BO); b1[0][1]=LDB(2,1,BO); \
                       b1[1][0]=LDB(3,0,BO); b1[1][1]=LDB(3,1,BO); } while (0)

#define MFMA1(R, NB, AF, KS, BF, NT) \
    acc[R][(NB)+(NT)] = __builtin_amdgcn_mfma_f32_16x16x32_bf16(AF, BF[NT][KS], acc[R][(NB)+(NT)], 0, 0, 0)

// 4 MFMAs consuming af[AFI] (ks0 both nt, then ks1 both nt — per-acc order ks0->ks1)
#define MMG_A(R, AFI, NB, BF) do { \
    MFMA1(R, NB, af[AFI][0], 0, BF, 0); MFMA1(R, NB, af[AFI][0], 0, BF, 1); \
    MFMA1(R, NB, af[AFI][1], 1, BF, 0); MFMA1(R, NB, af[AFI][1], 1, BF, 1); } while (0)

// full 16-MFMA cluster (prologue-fed phases / tail), per-acc order ks0->ks1
#define MMAQ(MB, NB, BF) do { \
    __builtin_amdgcn_s_setprio(1); \
    _Pragma("unroll") \
    for (int ks_ = 0; ks_ < 2; ++ks_) \
      _Pragma("unroll") \
      for (int mt_ = 0; mt_ < 4; ++mt_) \
        _Pragma("unroll") \
        for (int nt_ = 0; nt_ < 2; ++nt_) \
          acc[(MB)+mt_][(NB)+nt_] = __builtin_amdgcn_mfma_f32_16x16x32_bf16( \
              af[mt_][ks_], BF[nt_][ks_], acc[(MB)+mt_][(NB)+nt_], 0, 0, 0); \
    __builtin_amdgcn_s_setprio(0); } while (0)

// PH1: b1 dead -> read first, then pure MFMA cluster.
#define PH1(CUR,NXT,dN) do { VMC(8); BAR(); ST_U3(dN,NXT); RD_B1(CUR); \
    __builtin_amdgcn_s_setprio(1); \
    _Pragma("unroll") for (int mt_ = 0; mt_ < 4; ++mt_) MMG_A(mt_, mt_, 0, b0); \
    __builtin_amdgcn_s_setprio(0); \
    SGB(0x100, 4); SGB(0x8, 16); \
    BAR(); } while (0)

// PH2: groups of {4 MFMA on af[mt]} -> {reload af[mt] <- A47(CUR)}
#define PH2(CUR,dNN) do { VMC(8); BAR(); ST_U0(dNN,CUR); \
    _Pragma("unroll") for (int mt_ = 0; mt_ < 4; ++mt_) { \
        __builtin_amdgcn_s_setprio(1); MMG_A(mt_, mt_, 2, b1); __builtin_amdgcn_s_setprio(0); \
        af[mt_][0] = LDA(mt_,0,CUR,8192); af[mt_][1] = LDA(mt_,1,CUR,8192); } \
    SGB(0x8,4); SGB(0x100,2); SGB(0x8,4); SGB(0x100,2); \
    SGB(0x8,4); SGB(0x100,2); SGB(0x8,4); SGB(0x100,2); \
    BAR(); } while (0)

// PH3: groups of {8 MFMA on b0[nt]} -> {reload b0[nt] <- B0(NXT)}
#define PH3(CUR,NXT,dNN) do { VMC(6); BAR(); ST_U1(dNN,CUR); \
    _Pragma("unroll") for (int nt_ = 0; nt_ < 2; ++nt_) { \
        __builtin_amdgcn_s_setprio(1); \
        _Pragma("unroll") for (int mt_ = 0; mt_ < 4; ++mt_) { \
            MFMA1(4+mt_, 0, af[mt_][0], 0, b0, nt_); \
            MFMA1(4+mt_, 0, af[mt_][1], 1, b0, nt_); } \
        __builtin_amdgcn_s_setprio(0); \
        b0[nt_][0] = LDB(nt_,0,NXT); b0[nt_][1] = LDB(nt_,1,NXT); } \
    SGB(0x8,8); SGB(0x100,2); SGB(0x8,8); SGB(0x100,2); \
    BAR(); } while (0)

// PH4: groups of {4 MFMA on af[mt]} -> {reload af[mt] <- A03(NXT)}
#define PH4(CUR,NXT,dNN) do { VMC(10); BAR(); ST_U2(dNN,CUR); \
    _Pragma("unroll") for (int mt_ = 0; mt_ < 4; ++mt_) { \
        __builtin_amdgcn_s_setprio(1); MMG_A(4+mt_, mt_, 2, b1); __builtin_amdgcn_s_setprio(0); \
        af[mt_][0] = LDA(mt_,0,NXT,0); af[mt_][1] = LDA(mt_,1,NXT,0); } \
    SGB(0x8,4); SGB(0x100,2); SGB(0x8,4); SGB(0x100,2); \
    SGB(0x8,4); SGB(0x100,2); SGB(0x8,4); SGB(0x100,2); \
    BAR(); } while (0)

__global__ void __launch_bounds__(512, 2)
gemm_bf16_8phase(const short* __restrict__ A, const short* __restrict__ B,
                 const float* __restrict__ bias, float* __restrict__ C) {
    __shared__ __align__(16) char smem[131072];   // [buf][A 32K | B 32K]

    const int tid  = threadIdx.x;
    const int w    = tid >> 6;        // wave 0..7
    const int lane = tid & 63;
    const int wm   = w >> 2;          // 0..1
    const int wn   = w & 3;           // 0..3

    // T1: XCD-aware swizzle (512 wgs, 512%8==0 -> bijective)
    const int bid  = blockIdx.x;
    const int swz  = ((bid & 7) << 6) | (bid >> 3);
    const int row0 = (swz >> 4) << 8;   // M tile * 256
    const int col0 = (swz & 15) << 8;   // N tile * 256

    // ---- staging: per-lane pre-swizzled global src, wave-uniform linear LDS dest ----
    const int lrow = lane >> 3;                 // row within wave's 8-row slice
    const int lch  = (lane & 7) ^ lrow;         // swizzled k-chunk this lane fetches
    const short* gA = A + (int64_t)(row0 + w * 8 + lrow) * IN_F + lch * 8;
    const int bb   = w * 8 + (w >> 2) * 32;     // B row base: {0..31} u {64..95}
    const short* gB = B + (int64_t)(col0 + bb + lrow) * IN_F + lch * 8;
    const int lbA  = w * 1024;                  // A region base (bytes)
    const int lbB  = 32768 + bb * 128;          // B region base (bytes)

    // ---- read-side offsets (m89 fragment convention) ----
    const int ml = lane & 15;
    const int q4 = lane >> 4;
    const int offA0 = (wm * 128 + ml) * 128 + ((q4 ^ (lane & 7)) << 4);
    const int offA1 = offA0 ^ 64;
    const int offB0 = 32768 + (wn * 64 + ml) * 128 + ((q4 ^ (lane & 7)) << 4);
    const int offB1 = offB0 ^ 64;

    floatx4 acc[8][4];
#pragma unroll
    for (int i = 0; i < 8; ++i)
#pragma unroll
        for (int j = 0; j < 4; ++j) acc[i][j] = (floatx4)(0.0f);

    shortx8 af[4][2], b0[2][2], b1[2][2];

    // prologue: tile0 all 4 units -> buf0; tile1 U0-U2 -> buf1 (14 loads/wave).
    ST_U0(0, 0); ST_U1(0, 0); ST_U2(0, 0); ST_U3(0, 0);
    ST_U0(1, 65536); ST_U1(1, 65536); ST_U2(1, 65536);
    VMC(6);
    BAR();
    RD_A03(0);   // af03(0)
    RD_B0(0);    // b0(0)

#pragma unroll 1
    for (int it = 0; it < 31; ++it) {            // tiles 0..61; stages reach k-tile 63
        PH1(0, 65536, 1); PH2(0, 2); PH3(0, 65536, 2); PH4(0, 65536, 2);
        PH1(65536, 0, 2); PH2(65536, 3); PH3(65536, 0, 3); PH4(65536, 0, 3);
        gA += 128; gB += 128;                    // advance 2 K-tiles
    }
    // ---- tail: tile 62 (buf0) stages only U3(63); ladder as R3 (8/8/4/2/0) ----
    VMC(8); BAR(); ST_U3(1, 65536); RD_B1(0); MMAQ(0,0,b0);      BAR();
    VMC(8); BAR();                  MMAQ(0,2,b1); RD_A47(0);     BAR();
    VMC(4); BAR();                  MMAQ(4,0,b0); RD_B0(65536);  BAR();
    VMC(2); BAR();                  MMAQ(4,2,b1); RD_A03(65536); BAR();
    // ---- tile 63 (buf1): everything landed after VMC(0) ----
    VMC(0); BAR();
    RD_B1(65536);
    MMAQ(0,0,b0); MMAQ(0,2,b1);
    RD_A47(65536);                               // reg-WAR after MMAQ(0,2)
    MMAQ(4,0,b0); MMAQ(4,2,b1);

    // epilogue: C/D layout col = lane&15, row = (lane>>4)*4 + reg  [m89/m91]
#pragma unroll
    for (int nt = 0; nt < 4; ++nt) {
        const int gcol = col0 + wn * 64 + nt * 16 + ml;
        const float bv = bias[gcol];
#pragma unroll
        for (int mt = 0; mt < 8; ++mt) {
            const int grow = row0 + wm * 128 + mt * 16 + q4 * 4;
            float* outp = C + (int64_t)grow * OUT_F + gcol;
#pragma unroll
            for (int r = 0; r < 4; ++r)
                outp[(int64_t)r * OUT_F] = acc[mt][nt][r] + bv;
        }
    }
}

extern "C" void kernel_launch(void* const* d_in, const int* in_sizes, int n_in,
                              void* d_out, int out_size, void* d_ws, size_t ws_size,
                              hipStream_t stream) {
    const float* x    = (const float*)d_in[0];
    const int*   qw   = (const int*)d_in[1];
    const float* sc   = (const float*)d_in[2];
    const float* bias = (const float*)d_in[3];
    float*       out  = (float*)d_out;

    // workspace: [x_bf16: 64 MiB][w_bf16: 32 MiB]
    short* xb = (short*)d_ws;
    short* wb = (short*)((char*)d_ws + (size_t)MROWS * IN_F * sizeof(short));

    preprocess_kernel<<<PRE_XBLK + PRE_WBLK, 256, 0, stream>>>(
        x, xb, qw, sc, wb);

    gemm_bf16_8phase<<<dim3((MROWS / 256) * (OUT_F / 256)), dim3(512), 0, stream>>>(
        xb, wb, bias, out);
}